// Round 12
// baseline (74.671 us; speedup 1.0000x reference)
//
#include <hip/hip_runtime.h>
#include <hip/hip_bf16.h>

// SConv2dAvg: stride-2 conv with per-output-pixel stochastic tap selection.
// B=32 C=128 H=W=64, O=256 kh=kw=3, oh=ow=32, PAD=1, STRIDE=2.
//
// Round 12 — fused, non-draining barriers:
//  wprep: fp32 w -> bf16 wq[8cc][5pair][256o][4hst][8e]; content chunk
//    hi = hst ^ ((o>>1)&3)  (8-quad bank spread for FW reads, R4 pattern);
//    tap = 2*pair + (hi>>1) (tap 9 zero-padded), c = cc*16 + (hi&1)*8 + e.
//  sconv_fused2: grid 256 (1 blk/CU), 512 thr / 8 waves (4ox2p of 64x64).
//    Per 16-ch chunk: input slab NCHW->LDS transpose (scratch+PASS2), weights
//    global->reg->LDS, 80 MFMA/thread. ALL barriers = lgkmcnt(0)+sched_barrier
//    +raw s_barrier: LDS hazards fenced, global->reg loads NEVER drained —
//    they ride across barriers under COMPUTE with compiler-exact reg waits
//    (robust to spills; no hand-counted vmcnt). Slab stride 67 (odd) kills
//    the sel-random row conflicts.

typedef short bf16x8 __attribute__((ext_vector_type(8)));
typedef float f32x4  __attribute__((ext_vector_type(4)));

#define WQ_BYTES (40 * 256 * 64)    // 655360

__device__ __forceinline__ unsigned short f2bf(float x) {
  unsigned u = __float_as_uint(x);
  return (unsigned short)((u + 0x7fffu + ((u >> 16) & 1u)) >> 16);
}
__device__ __forceinline__ unsigned pk2(float a, float b) {
  unsigned ua = __float_as_uint(a), ub = __float_as_uint(b);
  return ((ua + 0x7fffu + ((ua >> 16) & 1u)) >> 16) |
         ((ub + 0x7fffu + ((ub >> 16) & 1u)) & 0xffff0000u);
}
__device__ __forceinline__ bf16x8 ld_frag(const uint4* a) {
  union { uint4 u; bf16x8 s; } cv; cv.u = *a; return cv.s;
}

// LDS fence: publish my ds ops, sync waves. Does NOT drain vmcnt — global
// loads in flight stay in flight (their consumers get compiler-exact waits).
#define LDSFENCE()                                                            \
  do {                                                                        \
    asm volatile("s_waitcnt lgkmcnt(0)" ::: "memory");                        \
    __builtin_amdgcn_sched_barrier(0);                                        \
    __builtin_amdgcn_s_barrier();                                             \
    __builtin_amdgcn_sched_barrier(0);                                        \
  } while (0)

// ---- weight repack: wq[cc*5+pair][o][hst][e] ----
__global__ __launch_bounds__(256) void wprep(const float* __restrict__ w,
                                             unsigned short* __restrict__ wq) {
  const int L   = (blockIdx.x << 8) + threadIdx.x;   // 0..655359
  const int e   = L & 7;
  const int hst = (L >> 3) & 3;
  const int o   = (L >> 5) & 255;
  const int t5  = L >> 13;                 // 0..39
  const int cc  = t5 / 5, pair = t5 - 5 * cc;
  const int hi  = hst ^ ((o >> 1) & 3);
  const int tap = 2 * pair + (hi >> 1);
  const int c   = (cc << 4) + ((hi & 1) << 3) + e;
  wq[L] = (tap <= 8) ? f2bf(w[(o * 128 + c) * 9 + tap]) : (unsigned short)0;
}

// ----------------------------- fused main ----------------------------------
__global__ __launch_bounds__(512, 2) void sconv_fused2(
    const float* __restrict__ in,            // [32][128][64][64] fp32
    const unsigned short* __restrict__ wq,   // 655360 B, pre-packed
    const float* __restrict__ bias,
    const int* __restrict__ selh,            // [32][32]
    const int* __restrict__ selw,            // [32][32]
    float* __restrict__ out)                 // [32][256][32][32]
{
  __shared__ uint4 Bbuf[5120];      // 80 KB: one c-chunk of weights (256 o)
  __shared__ uint4 slab[2][20 * 67];// 2 x 21.4 KB: [r2][col'] stride 67 (odd)
  __shared__ uint4 scratch[1280];   // 20 KB: bf16 [r10][c16][w64]
  __shared__ float bias_s[256];

  const int tid = threadIdx.x;
  const int d0  = blockIdx.x;
  const int blk = ((d0 & 7) << 5) | (d0 >> 3);
  const int b   = blk >> 3;
  const int y0  = (blk & 7) << 2;             // 4 output rows

  if (tid < 256) bias_s[tid] = bias[tid];

  const int wv = tid >> 6, ln = tid & 63;
  const int lo = ln & 15, hi = ln >> 4;
  const int wo = wv >> 1, wp = wv & 1;        // 4 o-waves x 2 p-waves (64x64)
  const int h2 = hi >> 1, ch = hi & 1;        // tap-in-pair, c-half

  // per-frag pixel constants (sel folded into LDS addressing)
  int pr[4], pc[4];
#pragma unroll
  for (int f = 0; f < 4; ++f) {
    const int pxl = (wp << 6) + (f << 4) + lo;     // 0..127
    const int py  = y0 + (pxl >> 5), px = pxl & 31;
    pr[f] = ((pxl >> 5) << 1) + selh[(py << 5) | px];   // 0..7
    pc[f] = (px << 1) + selw[(py << 5) | px];           // 0..63 (padded col-1)
  }
  const float* inb = in + ((size_t)b << 19);
  int Obase[4];
#pragma unroll
  for (int fo = 0; fo < 4; ++fo) {
    const int O = (wo << 6) + (fo << 4) + lo;
    Obase[fo] = (O << 2) + (hi ^ ((O >> 1) & 3));
  }

  f32x4 acc[4][4] = {};
  float4 ar[5]; uint4 br[10];
  const float4 z4 = make_float4(0.f, 0.f, 0.f, 0.f);

#define LOAD_A(CC)                                                            \
  do {                                                                        \
    _Pragma("unroll")                                                         \
    for (int i = 0; i < 5; ++i) {                                             \
      const int q = tid + (i << 9);          /* 2560 quads */                 \
      const int c = ((CC) << 4) + ((q >> 4) & 15);                            \
      const int h = (y0 << 1) - 1 + (q >> 8);                                 \
      ar[i] = (h >= 0 && h < 64)                                              \
          ? *(const float4*)(inb + ((size_t)c << 12) + (h << 6) + ((q & 15) << 2)) \
          : z4;                                                               \
    }                                                                         \
  } while (0)

#define WRITE_SCRATCH()                                                       \
  do {                                                                        \
    _Pragma("unroll")                                                         \
    for (int i = 0; i < 5; ++i) {                                             \
      const int q = tid + (i << 9);                                           \
      uint2 d2; d2.x = pk2(ar[i].x, ar[i].y); d2.y = pk2(ar[i].z, ar[i].w);   \
      *(uint2*)((char*)scratch + q * 8) = d2;                                 \
    }                                                                         \
  } while (0)

  // scratch bf16 [r][c16][w]: transpose-read 8 c's per w-pair -> 2 slab cells
  // slab row stride 67; even padded col 2m -> slot m, odd 2m+1 -> slot 34+m.
#define PASS2(DST)                                                            \
  do {                                                                        \
    _Pragma("unroll")                                                         \
    for (int rep = 0; rep < 2; ++rep) {                                       \
      const int s2 = tid + (rep << 9);                                        \
      if (s2 < 640) {                                                         \
        const int r = s2 >> 6, rem = s2 & 63;                                 \
        const int chp = rem >> 5, w2 = rem & 31;                              \
        unsigned u[8];                                                        \
        _Pragma("unroll")                                                     \
        for (int i = 0; i < 8; ++i)                                           \
          u[i] = *(const unsigned*)((const char*)scratch +                    \
                   ((r << 4) + (chp << 3) + i) * 128 + (w2 << 2));            \
        uint4 ev, od;                                                         \
        ev.x = (u[0] & 0xffffu) | (u[1] << 16);                               \
        ev.y = (u[2] & 0xffffu) | (u[3] << 16);                               \
        ev.z = (u[4] & 0xffffu) | (u[5] << 16);                               \
        ev.w = (u[6] & 0xffffu) | (u[7] << 16);                               \
        od.x = (u[0] >> 16) | (u[1] & 0xffff0000u);                           \
        od.y = (u[2] >> 16) | (u[3] & 0xffff0000u);                           \
        od.z = (u[4] >> 16) | (u[5] & 0xffff0000u);                           \
        od.w = (u[6] >> 16) | (u[7] & 0xffff0000u);                           \
        const int r2 = ((r << 1) + chp) * 67;                                 \
        slab[DST][r2 + w2 + 34] = ev;   /* col=2w2+1 (odd)  -> 34+w2 */       \
        slab[DST][r2 + w2 + 1]  = od;   /* col=2w2+2 (even) -> w2+1  */       \
      }                                                                       \
    }                                                                         \
    if (tid < 40) {                        /* halo cols 0 and 65 -> zero */   \
      uint4 zz; zz.x = zz.y = zz.z = zz.w = 0u;                               \
      slab[DST][(tid >> 1) * 67 + ((tid & 1) ? 66 : 0)] = zz;                 \
    }                                                                         \
  } while (0)

#define LOAD_B(CC)                                                            \
  do {                                                                        \
    _Pragma("unroll")                                                         \
    for (int i = 0; i < 10; ++i)                                              \
      br[i] = *(const uint4*)((const char*)wq + (size_t)(CC) * 81920 +        \
                              ((tid + (i << 9)) << 4));                       \
  } while (0)

#define WRITE_B()                                                             \
  do {                                                                        \
    _Pragma("unroll")                                                         \
    for (int i = 0; i < 10; ++i) Bbuf[tid + (i << 9)] = br[i];                \
  } while (0)

#define COMPUTE(SB)                                                           \
  do {                                                                        \
    _Pragma("unroll")                                                         \
    for (int pair = 0; pair < 5; ++pair) {                                    \
      bf16x8 FW[4], FP[4];                                                    \
      _Pragma("unroll")                                                       \
      for (int fo = 0; fo < 4; ++fo)                                          \
        FW[fo] = ld_frag(Bbuf + (pair << 10) + Obase[fo]);                    \
      int tap = (pair << 1) + h2; if (tap > 8) tap = 8;                       \
      const int di = (tap >= 6) ? 2 : ((tap >= 3) ? 1 : 0);                   \
      const int dj = tap - 3 * di;                                            \
      _Pragma("unroll")                                                       \
      for (int f = 0; f < 4; ++f) {                                           \
        const int col  = pc[f] + dj;                                          \
        const int colp = (col >> 1) + ((col & 1) ? 34 : 0);                   \
        FP[f] = ld_frag(&slab[SB][(((pr[f] + di) << 1) + ch) * 67 + colp]);   \
      }                                                                       \
      __builtin_amdgcn_s_setprio(1);                                          \
      _Pragma("unroll")                                                       \
      for (int fo = 0; fo < 4; ++fo)                                          \
        _Pragma("unroll")                                                     \
        for (int f = 0; f < 4; ++f)                                           \
          acc[fo][f] = __builtin_amdgcn_mfma_f32_16x16x32_bf16(               \
              FW[fo], FP[f], acc[fo][f], 0, 0, 0);                            \
      __builtin_amdgcn_s_setprio(0);                                          \
    }                                                                         \
  } while (0)

  // ---- prologue: build slab[0] for chunk 0; start B(0), A(1) in flight ----
  LOAD_A(0);
  WRITE_SCRATCH();                 // compiler waits ar's vmcnt exactly
  LDSFENCE();                      // scratch(0) published
  PASS2(0);
  LOAD_B(0);
  LOAD_A(1);
  LDSFENCE();                      // slab[0] published (B/A loads in flight)

  // ---- 8 phases; 2 LDS fences each; vmem never force-drained ----
  for (int cc = 0; cc < 8; ++cc) {
    WRITE_B();                     // br = B(cc); waits its loads only
    if (cc < 7) WRITE_SCRATCH();   // ar = A(cc+1)
    LDSFENCE();                    // Bbuf(cc) + scratch(cc+1) published
    if (cc < 7) LOAD_B(cc + 1);    // issue early: ride under COMPUTE
    if (cc < 6) LOAD_A(cc + 2);
    if (cc < 7) PASS2((cc + 1) & 1);
    COMPUTE(cc & 1);               // 40 ds_read_b128 + 80 MFMA
    if (cc < 7) LDSFENCE();        // slab[(cc+1)&1] published; reads drained
  }

  // ---- epilogue: D row = o (hi*4+j), col = pix (lo); +bias
  float* ob = out + ((size_t)b << 18) + (y0 << 5);
#pragma unroll
  for (int fo = 0; fo < 4; ++fo) {
    const int obase = (wo << 6) + (fo << 4) + (hi << 2);
#pragma unroll
    for (int f = 0; f < 4; ++f) {
      const int P = (wp << 6) + (f << 4) + lo;
#pragma unroll
      for (int j = 0; j < 4; ++j) {
        const int o = obase + j;
        ob[((size_t)o << 10) + P] = acc[fo][f][j] + bias_s[o];
      }
    }
  }
#undef LOAD_A
#undef WRITE_SCRATCH
#undef PASS2
#undef LOAD_B
#undef WRITE_B
#undef COMPUTE
}

// ------------------- exact fp32 fallback (ws too small) --------------------
__global__ __launch_bounds__(256) void sconv_naive(
    const float* __restrict__ in, const float* __restrict__ w,
    const float* __restrict__ bias, const int* __restrict__ selh,
    const int* __restrict__ selw, float* __restrict__ out) {
  int idx = (blockIdx.x << 8) + threadIdx.x;
  if (idx >= 32 * 256 * 32 * 32) return;
  int x = idx & 31, y = (idx >> 5) & 31, o = (idx >> 10) & 255, b = idx >> 18;
  int rh0 = 2 * y + selh[(y << 5) | x] - 1;
  int rw0 = 2 * x + selw[(y << 5) | x] - 1;
  const float* inb = in + ((size_t)b << 19);
  const float* wo_ = w + o * 1152;
  float acc = bias[o];
  for (int c = 0; c < 128; ++c)
    for (int i = 0; i < 3; ++i) {
      int rh = rh0 + i;
      if (rh < 0 || rh >= 64) continue;
      for (int j = 0; j < 3; ++j) {
        int rw = rw0 + j;
        if (rw < 0 || rw >= 64) continue;
        acc += inb[(c << 12) + (rh << 6) + rw] * wo_[c * 9 + i * 3 + j];
      }
    }
  out[idx] = acc;
}

extern "C" void kernel_launch(void* const* d_in, const int* in_sizes, int n_in,
                              void* d_out, int out_size, void* d_ws, size_t ws_size,
                              hipStream_t stream) {
  const float* in   = (const float*)d_in[0];
  const float* w    = (const float*)d_in[1];
  const float* bias = (const float*)d_in[2];
  const int*   selh = (const int*)d_in[3];
  const int*   selw = (const int*)d_in[4];
  float* out = (float*)d_out;

  if (ws_size >= (size_t)WQ_BYTES) {
    unsigned short* wq = (unsigned short*)d_ws;
    wprep<<<dim3(2560), dim3(256), 0, stream>>>(w, wq);
    sconv_fused2<<<dim3(256), dim3(512), 0, stream>>>(in, wq, bias, selh, selw, out);
  } else {
    sconv_naive<<<dim3(32768), dim3(256), 0, stream>>>(in, w, bias, selh, selw, out);
  }
}